// Round 6
// baseline (171.326 us; speedup 1.0000x reference)
//
#include <hip/hip_runtime.h>
#include <stdint.h>

typedef int v4i __attribute__((ext_vector_type(4)));

#define AS1(p) ((const __attribute__((address_space(1))) void*)(p))
#define AS3(p) ((__attribute__((address_space(3))) void*)(p))

// ---------------- quantize x: fp32 -> int8 ----------------
__global__ __launch_bounds__(256) void quant_x_kernel(
    const float* __restrict__ x, int8_t* __restrict__ xq,
    const float* __restrict__ s_p, const int* __restrict__ izp_p, int n16)
{
    int t = blockIdx.x * 256 + threadIdx.x;
    if (t >= n16) return;
    float s = *s_p;
    float zp = (float)(*izp_p);
    const float4* xin = (const float4*)x + (size_t)t * 4;
    int words[4];
#pragma unroll
    for (int i = 0; i < 4; ++i) {
        float4 v = xin[i];
        // round-half-even like jnp.round; exact IEEE division like the reference
        float q0 = fminf(127.f, fmaxf(-128.f, rintf(v.x / s) + zp));
        float q1 = fminf(127.f, fmaxf(-128.f, rintf(v.y / s) + zp));
        float q2 = fminf(127.f, fmaxf(-128.f, rintf(v.z / s) + zp));
        float q3 = fminf(127.f, fmaxf(-128.f, rintf(v.w / s) + zp));
        words[i] = ((int)q0 & 255) | (((int)q1 & 255) << 8) |
                   (((int)q2 & 255) << 16) | (((int)q3 & 255) << 24);
    }
    ((int4*)xq)[t] = make_int4(words[0], words[1], words[2], words[3]);
}

// ---------------- pack weight: int32 -> int8 ----------------
__global__ __launch_bounds__(256) void pack_w_kernel(
    const int* __restrict__ w, int8_t* __restrict__ w8, int n4)
{
    int t = blockIdx.x * 256 + threadIdx.x;
    if (t >= n4) return;
    int4 v = ((const int4*)w)[t];
    ((int*)w8)[t] = (v.x & 255) | ((v.y & 255) << 8) |
                    ((v.z & 255) << 16) | ((v.w & 255) << 24);
}

// ---------------- int8 GEMM: 256x256 tile, BK=128, 8 waves, 4-phase/K-tile ----------------
// 8-phase-template port (T2+T3+T4+T5): double-buffered LDS, counted vmcnt (never
// drain mid-loop), per-phase {ds_read || stage -> barrier -> MFMA cluster -> barrier}.
#define GM 65536
#define GN 1024
#define GK 1024
#define NT 8    // K-tiles of 128

__global__ __launch_bounds__(512, 2) void gemm_i8_kernel(
    const int8_t* __restrict__ A,   // [GM][GK]
    const int8_t* __restrict__ B,   // [GN][GK]
    const int* __restrict__ bias,
    const float* __restrict__ osc_p, const int* __restrict__ ozp_p,
    float* __restrict__ out)
{
    // tile: 256 rows x 128 B; row = 8 slots of 16 B; phys slot = logical ^ (row&7)
    __shared__ int8_t As[2][32768];
    __shared__ int8_t Bs[2][32768];

    const int tid = threadIdx.x;              // 0..511
    const int w   = tid >> 6, l = tid & 63;
    const int wm  = w >> 2,  wn = w & 3;      // 2x4 wave grid, per-wave out 128x64
    const int r15 = l & 15,  s4 = l >> 4;

    // XCD-bijective: wg%8 = XCD, each XCD gets 128 consecutive logical blocks;
    // 4 consecutive logical blocks = one bm-panel x all 4 bn (A panel L2-reused).
    const int wg = blockIdx.x;                 // 0..1023
    const int lg = ((wg & 7) << 7) + (wg >> 3);
    const int bm0 = (lg >> 2) << 8;
    const int bn0 = (lg & 3) << 8;

    // Staging (shot = 8 KB = 64 rows): thread covers row c*64+(tid>>3), 16 B at
    // phys slot tid&7; global col pre-swizzled: logical slot = (tid&7)^((tid>>3)&7).
    const int srow = tid >> 3;
    const int gcol = (((tid & 7) ^ ((tid >> 3) & 7)) << 4);
    const int8_t* aS = A + (size_t)(bm0 + srow) * GK + gcol;
    const int8_t* bS = B + (size_t)(bn0 + srow) * GK + gcol;

#define SHOT_A(T, BUF, C) __builtin_amdgcn_global_load_lds( \
    AS1(aS + (size_t)(C) * 64 * GK + (T) * 128), \
    AS3(&As[BUF][(C) * 8192 + w * 1024]), 16, 0, 0)
#define SHOT_B(T, BUF, C) __builtin_amdgcn_global_load_lds( \
    AS1(bS + (size_t)(C) * 64 * GK + (T) * 128), \
    AS3(&Bs[BUF][(C) * 8192 + w * 1024]), 16, 0, 0)

    // Fragment read bases (same XOR on read; key = r15&7). Row steps are
    // compile-time immediates: +2048/row-of-16, +4096/quadrant.
    const int akey = r15 & 7;
    const int a_rd0 = ((wm * 128 + r15) << 7) + (((0 + s4) ^ akey) << 4);
    const int a_rd1 = ((wm * 128 + r15) << 7) + (((4 + s4) ^ akey) << 4);
    const int b_rd0 = ((wn * 64 + r15) << 7) + (((0 + s4) ^ akey) << 4);
    const int b_rd1 = ((wn * 64 + r15) << 7) + (((4 + s4) ^ akey) << 4);

    v4i acc[8][4];
#pragma unroll
    for (int i = 0; i < 8; ++i)
#pragma unroll
        for (int j = 0; j < 4; ++j) acc[i][j] = (v4i){0, 0, 0, 0};

    v4i bfr[4][2];   // B frags cached per K-tile (static indexing only)

#define LOADB(CUR) do { \
    _Pragma("unroll") \
    for (int j = 0; j < 4; ++j) { \
        bfr[j][0] = *(const v4i*)&Bs[CUR][b_rd0 + j * 2048]; \
        bfr[j][1] = *(const v4i*)&Bs[CUR][b_rd1 + j * 2048]; \
    } \
} while (0)

// Phase Q: rows 2Q,2Q+1 of the 8-row wave tile; 16 MFMA between barriers.
#define PHASE(CUR, Q, ...) do { \
    v4i af0 = *(const v4i*)&As[CUR][a_rd0 + (Q) * 4096]; \
    v4i af1 = *(const v4i*)&As[CUR][a_rd1 + (Q) * 4096]; \
    v4i af2 = *(const v4i*)&As[CUR][a_rd0 + (Q) * 4096 + 2048]; \
    v4i af3 = *(const v4i*)&As[CUR][a_rd1 + (Q) * 4096 + 2048]; \
    __VA_ARGS__; \
    __builtin_amdgcn_s_barrier(); \
    __builtin_amdgcn_s_setprio(1); \
    _Pragma("unroll") \
    for (int j = 0; j < 4; ++j) { \
        acc[(Q)*2][j]     = __builtin_amdgcn_mfma_i32_16x16x64_i8(af0, bfr[j][0], acc[(Q)*2][j], 0, 0, 0); \
        acc[(Q)*2][j]     = __builtin_amdgcn_mfma_i32_16x16x64_i8(af1, bfr[j][1], acc[(Q)*2][j], 0, 0, 0); \
        acc[(Q)*2 + 1][j] = __builtin_amdgcn_mfma_i32_16x16x64_i8(af2, bfr[j][0], acc[(Q)*2 + 1][j], 0, 0, 0); \
        acc[(Q)*2 + 1][j] = __builtin_amdgcn_mfma_i32_16x16x64_i8(af3, bfr[j][1], acc[(Q)*2 + 1][j], 0, 0, 0); \
    } \
    __builtin_amdgcn_s_setprio(0); \
    __builtin_amdgcn_s_barrier(); \
} while (0)

// Iter T: entry = all of tile T issued (during T-1), none of T+1.
// Issue 2 shots of T+1 FIRST, then vmcnt(2) == "tile T landed" (no drain).
// Remaining 6 shots spread over phases 0-2. Staging writes go to buf nxt,
// whose last reads (tile T-1) finished before the previous iter's last barrier.
#define BODY(T, SON) do { \
    const int cur_ = (T) & 1, nxt_ = cur_ ^ 1; \
    if (SON) { \
        SHOT_A((T) + 1, nxt_, 0); SHOT_A((T) + 1, nxt_, 1); \
        asm volatile("s_waitcnt vmcnt(2)" ::: "memory"); \
    } else { \
        asm volatile("s_waitcnt vmcnt(0)" ::: "memory"); \
    } \
    __builtin_amdgcn_s_barrier(); \
    __builtin_amdgcn_sched_barrier(0); \
    LOADB(cur_); \
    PHASE(cur_, 0, if (SON) { SHOT_A((T) + 1, nxt_, 2); SHOT_A((T) + 1, nxt_, 3); }); \
    PHASE(cur_, 1, if (SON) { SHOT_B((T) + 1, nxt_, 0); SHOT_B((T) + 1, nxt_, 1); }); \
    PHASE(cur_, 2, if (SON) { SHOT_B((T) + 1, nxt_, 2); SHOT_B((T) + 1, nxt_, 3); }); \
    PHASE(cur_, 3, ); \
} while (0)

    // Prologue: stage tile 0 fully (8 shots)
#pragma unroll
    for (int c = 0; c < 4; ++c) { SHOT_A(0, 0, c); SHOT_B(0, 0, c); }

#pragma unroll 1
    for (int t = 0; t < NT - 1; ++t) BODY(t, 1);
    BODY(NT - 1, 0);

#undef BODY
#undef PHASE
#undef LOADB
#undef SHOT_A
#undef SHOT_B

    const float osc = *osc_p;
    const int   ozp = *ozp_p;
    int bj[4];
#pragma unroll
    for (int j = 0; j < 4; ++j)
        bj[j] = bias[bn0 + wn * 64 + j * 16 + r15] - ozp;

    // C/D layout (16x16): col = l&15, row = (l>>4)*4 + reg
#pragma unroll
    for (int i = 0; i < 8; ++i) {
        const int mrow = bm0 + wm * 128 + i * 16 + s4 * 4;
#pragma unroll
        for (int j = 0; j < 4; ++j) {
            const int n = bn0 + wn * 64 + j * 16 + r15;
            float* op = out + (size_t)mrow * GN + n;
#pragma unroll
            for (int r = 0; r < 4; ++r)
                __builtin_nontemporal_store((float)(acc[i][j][r] + bj[j]) * osc,
                                            op + (size_t)r * GN);
        }
    }
}

extern "C" void kernel_launch(void* const* d_in, const int* in_sizes, int n_in,
                              void* d_out, int out_size, void* d_ws, size_t ws_size,
                              hipStream_t stream)
{
    const float* x         = (const float*)d_in[0];
    const int*   w_int     = (const int*)d_in[1];
    const int*   b_int     = (const int*)d_in[2];
    const float* in_scale  = (const float*)d_in[3];
    const float* out_scale = (const float*)d_in[4];
    const int*   izp       = (const int*)d_in[5];
    const int*   ozp       = (const int*)d_in[6];
    float* out = (float*)d_out;

    int8_t* xq = (int8_t*)d_ws;                            // 64 MB
    int8_t* w8 = (int8_t*)d_ws + (size_t)64 * 1024 * 1024; // 1 MB

    quant_x_kernel<<<16384, 256, 0, stream>>>(x, xq, in_scale, izp, 4194304);
    pack_w_kernel<<<1024, 256, 0, stream>>>(w_int, w8, 262144);
    gemm_i8_kernel<<<1024, 512, 0, stream>>>(xq, w8, b_int, out_scale, ozp, out);
}